// Round 1
// baseline (657.237 us; speedup 1.0000x reference)
//
#include <hip/hip_runtime.h>
#include <math.h>

#define N 1024
#define BATCH 16
#define CH 3
#define BC 48
#define OUTHW 224
#define KSCALE (1024.0f / 224.0f)
#define SCALE  (224.0f / 1024.0f)
#define ABYTES ((size_t)BC * N * N * 8)      // 384 MiB complex workspace
#define T1OFF  (768 * 2048)                  // float offset of T1 inside each image's slab
#define WBAR() __builtin_amdgcn_wave_barrier()

// (ar,ai)*(br,bi) -> (dr,di); safe when d aliases a
#define CMUL(dr, di, ar, ai, br, bi) do {                         \
    float _r = (ar) * (br) - (ai) * (bi);                         \
    float _i = (ar) * (bi) + (ai) * (br);                         \
    (dr) = _r; (di) = _i; } while (0)

// forward DFT-4
#define RADIX4(ar,ai,br,bi,cr,ci,dr,di, o0r,o0i,o1r,o1i,o2r,o2i,o3r,o3i) do { \
    float u0r=(ar)+(cr), u0i=(ai)+(ci);                           \
    float u1r=(ar)-(cr), u1i=(ai)-(ci);                           \
    float u2r=(br)+(dr), u2i=(bi)+(di);                           \
    float u3r=(bi)-(di), u3i=(dr)-(br);                           \
    (o0r)=u0r+u2r; (o0i)=u0i+u2i;                                 \
    (o1r)=u1r+u3r; (o1i)=u1i+u3i;                                 \
    (o2r)=u0r-u2r; (o2i)=u0i-u2i;                                 \
    (o3r)=u1r-u3r; (o3i)=u1i-u3i; } while (0)

// In-register natural-order 16-pt forward DFT (Stockham radix-4 x radix-4).
__device__ __forceinline__ void dft16(float* xr, float* xi) {
  const float W16R[4][4] = {
    {1.f, 1.f, 1.f, 1.f},
    {1.f,  0.9238795325f,  0.7071067812f,  0.3826834324f},
    {1.f,  0.7071067812f,  0.0f,          -0.7071067812f},
    {1.f,  0.3826834324f, -0.7071067812f, -0.9238795325f}};
  const float W16I[4][4] = {
    {0.f, 0.f, 0.f, 0.f},
    {0.f, -0.3826834324f, -0.7071067812f, -0.9238795325f},
    {0.f, -0.7071067812f, -1.0f,          -0.7071067812f},
    {0.f, -0.9238795325f, -0.7071067812f,  0.3826834324f}};
  float tr[16], ti[16];
#pragma unroll
  for (int j = 0; j < 4; ++j) {
    RADIX4(xr[j],xi[j], xr[j+4],xi[j+4], xr[j+8],xi[j+8], xr[j+12],xi[j+12],
           tr[4*j],ti[4*j], tr[4*j+1],ti[4*j+1], tr[4*j+2],ti[4*j+2], tr[4*j+3],ti[4*j+3]);
  }
#pragma unroll
  for (int j = 0; j < 4; ++j) {
    float ar[4], ai_[4];
#pragma unroll
    for (int k = 0; k < 4; ++k) {
      if (j == 0 || k == 0) { ar[k] = tr[j+4*k]; ai_[k] = ti[j+4*k]; }
      else CMUL(ar[k], ai_[k], tr[j+4*k], ti[j+4*k], W16R[j][k], W16I[j][k]);
    }
    RADIX4(ar[0],ai_[0], ar[1],ai_[1], ar[2],ai_[2], ar[3],ai_[3],
           xr[j],xi[j], xr[j+4],xi[j+4], xr[j+8],xi[j+8], xr[j+12],xi[j+12]);
  }
}

// ---- 1024-pt wave FFT, decomposed into stages so two independent columns can
// time-share one LDS buffer (in-order DS pipe; WBAR = compiler fence only) ----
__device__ __forceinline__ void ex1_store(const float* xr, const float* xi,
                                          float* sre, float* sim, int l) {
#pragma unroll
  for (int k = 0; k < 16; ++k) { sre[17*l + k] = xr[k]; sim[17*l + k] = xi[k]; }
}
__device__ __forceinline__ void ex1_load(float* xr, float* xi,
                                         const float* sre, const float* sim, int base2) {
#pragma unroll
  for (int k = 0; k < 16; ++k) { xr[k] = sre[base2 + 68*k]; xi[k] = sim[base2 + 68*k]; }
}
__device__ __forceinline__ void stage2(float* xr, float* xi,
                                       const float2* __restrict__ twg, int j2) {
#pragma unroll
  for (int k = 1; k < 16; ++k) {
    float2 w = twg[4 * j2 * k];
    CMUL(xr[k], xi[k], xr[k], xi[k], w.x, w.y);
  }
  dft16(xr, xi);
}
__device__ __forceinline__ void ex2_store(const float* xr, const float* xi,
                                          float* sre, float* sim, int ob) {
#pragma unroll
  for (int k = 0; k < 16; ++k) { sre[ob + 17*k] = xr[k]; sim[ob + 17*k] = xi[k]; }
}
__device__ __forceinline__ void stage3(float* xr, float* xi,
                                       const float* sre, const float* sim,
                                       const float2* __restrict__ twg, int base2, int l) {
#pragma unroll
  for (int m = 0; m < 4; ++m) {
    float ar[4], ai_[4];
#pragma unroll
    for (int k = 0; k < 4; ++k) {
      ar[k] = sre[base2 + 68*m + 272*k];
      ai_[k] = sim[base2 + 68*m + 272*k];
    }
    const int j = l + 64*m;
#pragma unroll
    for (int k = 1; k < 4; ++k) {
      float2 w = twg[j * k];
      CMUL(ar[k], ai_[k], ar[k], ai_[k], w.x, w.y);
    }
    RADIX4(ar[0],ai_[0], ar[1],ai_[1], ar[2],ai_[2], ar[3],ai_[3],
           xr[m],xi[m], xr[m+4],xi[m+4], xr[m+8],xi[m+8], xr[m+12],xi[m+12]);
  }
}

// single-column FFT (used by k_rowfft; identical semantics to previous version)
__device__ __forceinline__ void wave_fft1024(float* xr, float* xi,
                                             float* sre, float* sim,
                                             const float2* __restrict__ twg, int l) {
  const int base2 = l + (l >> 4);
  const int j2 = l & 15;
  const int ob = 272 * (l >> 4) + j2;
  dft16(xr, xi);
  ex1_store(xr, xi, sre, sim, l); WBAR();
  ex1_load(xr, xi, sre, sim, base2);
  stage2(xr, xi, twg, j2);
  ex2_store(xr, xi, sre, sim, ob); WBAR();
  stage3(xr, xi, sre, sim, twg, base2, l);
}

__global__ void k_init(float2* __restrict__ tw, int* __restrict__ mnmx) {
  int g = blockIdx.x * 256 + threadIdx.x;
  if (g < 1024) {
    float ang = -6.283185307179586f * ((float)g / 1024.0f);
    float s, c;
    sincosf(ang, &s, &c);
    tw[g] = make_float2(c, s);
  }
  if (g < BATCH) mnmx[g] = 0x7F800000;       // +inf (min slots)
  else if (g < 2 * BATCH) mnmx[g] = 0;       // 0 (max slots; spec >= 0)
}

// Pass 1: unchanged — packed row-pair FFT + Hermitian unpack + transposed write.
__global__ __launch_bounds__(256, 4) void k_rowfft(const float* __restrict__ in,
                                                   float2* __restrict__ A,
                                                   const float2* __restrict__ twg) {
  __shared__ float lds[8704];
  const int t  = threadIdx.x;
  const int w  = t >> 6;
  const int l  = t & 63;
  const int bc  = blockIdx.x >> 7;
  const int h0b = (blockIdx.x & 127) << 3;
  const int r0  = h0b + 2 * w;
  float* sre = lds + w * 2176;
  float* sim = sre + 1088;
  const float* row0 = in + ((size_t)bc << 20) + ((size_t)r0 << 10);
  const float* row1 = row0 + N;
  float xr[16], xi[16];
  const float sgn = (l & 1) ? -1.0f : 1.0f;
#pragma unroll
  for (int k = 0; k < 16; ++k) {
    xr[k] =  sgn * row0[l + 64*k];
    xi[k] = -sgn * row1[l + 64*k];
  }
  wave_fft1024(xr, xi, sre, sim, twg, l);
#pragma unroll
  for (int s = 0; s < 16; ++s) { sre[l + 64*s] = xr[s]; sim[l + 64*s] = xi[s]; }
  WBAR();
  float arr[9], ari[9], brr[9], bri[9];
#pragma unroll
  for (int s = 0; s < 9; ++s) {
    int i  = l + 64*s;
    int nk = (N - i) & (N - 1);
    float pr = xr[s], pi = xi[s];
    float qr = sre[nk], qi = sim[nk];
    arr[s] = 0.5f * (pr + qr); ari[s] = 0.5f * (pi - qi);
    brr[s] = 0.5f * (pi + qi); bri[s] = 0.5f * (qr - pr);
  }
  __syncthreads();
  float* stre = lds;
  float* stim = lds + 4160;
#pragma unroll
  for (int s = 0; s < 9; ++s) {
    int i = l + 64*s;
    if (i <= 512) {
      stre[(2*w)     * 520 + i] = arr[s]; stim[(2*w)     * 520 + i] = ari[s];
      stre[(2*w + 1) * 520 + i] = brr[s]; stim[(2*w + 1) * 520 + i] = bri[s];
    }
  }
  __syncthreads();
  const int rr = t & 7, v0 = t >> 3;
  float2* Abc = A + ((size_t)bc << 20);
#pragma unroll
  for (int i2 = 0; i2 < 17; ++i2) {
    int v = v0 + 32 * i2;
    if (v <= 512) {
      Abc[(size_t)v * N + h0b + rr] = make_float2(stre[rr*520 + v], stim[rr*520 + v]);
    }
  }
}

// Fixed 10-tap fused resize for one spectrum column resident in LDS (spec[0..1023]).
// Window width 2*KSCALE < 10 taps; out-of-range taps masked to weight 0.
__device__ __forceinline__ void fused_resize_col(const float* spec, float* T1,
                                                 int sx, bool mir, int l) {
#pragma unroll
  for (int obk = 0; obk < 4; ++obk) {
    int oh = l + 64 * obk;
    if (oh < OUTHW) {
      float x = ((float)oh + 0.5f) * KSCALE - 0.5f;
      int jlo = (int)ceilf(x - KSCALE);           // unclamped
      float ssum = 0.0f, acc = 0.0f, accm = 0.0f;
#pragma unroll
      for (int u = 0; u < 10; ++u) {
        int j = jlo + u;
        float wgt = 1.0f - fabsf((float)j - x) * SCALE;
        wgt = fmaxf(wgt, 0.0f);
        bool valid = (j >= 0) && (j <= N - 1);
        if (!valid) wgt = 0.0f;
        int ja = valid ? j : 0;
        ssum += wgt;
        acc  += wgt * spec[ja];
        accm += wgt * spec[(N - ja) & (N - 1)];
      }
      float inv = 1.0f / ssum;
      T1[(size_t)sx * OUTHW + oh] = acc * inv;
      if (mir) T1[(size_t)(N - sx) * OUTHW + oh] = accm * inv;
    }
  }
}

// Pass 2: TWO columns per wave. The two FFTs time-share one per-wave LDS buffer
// (DS pipe is in-order within a wave, so st(c1) issued after ld(c0) is safe);
// each column's register-resident DFT-16/twiddle work fills the other column's
// LDS latency. Specs park in the re/im halves (c0->sre, c1->sim) for the
// unrolled 10-tap gather.
__global__ __launch_bounds__(256, 3) void k_colfft(const float2* __restrict__ A,
                                                   float* __restrict__ WSf,
                                                   int* __restrict__ mnmx,
                                                   const float2* __restrict__ twg) {
  __shared__ float lds[8704];
  const int t = threadIdx.x;
  const int w = t >> 6;
  const int l = t & 63;
  const int p = blockIdx.x * 4 + w;           // pair index 0..12311
  const int f0 = 2 * p, f1 = 2 * p + 1;       // flat column ids 0..24623
  const int bc0 = f0 / 513, sx0 = f0 - bc0 * 513;
  const int bc1 = f1 / 513, sx1 = f1 - bc1 * 513;
  float* sre = lds + w * 2176;
  float* sim = sre + 1088;
  const float2* s0 = A + ((size_t)bc0 << 20) + ((size_t)sx0 << 10);
  const float2* s1 = A + ((size_t)bc1 << 20) + ((size_t)sx1 << 10);
  float xr0[16], xi0[16], xr1[16], xi1[16];
#pragma unroll
  for (int k = 0; k < 16; ++k) { float2 v = s0[l + 64*k]; xr0[k] = v.x; xi0[k] = v.y; }
#pragma unroll
  for (int k = 0; k < 16; ++k) { float2 v = s1[l + 64*k]; xr1[k] = v.x; xi1[k] = v.y; }
  const int base2 = l + (l >> 4);
  const int j2 = l & 15;
  const int ob = 272 * (l >> 4) + j2;

  dft16(xr0, xi0);
  dft16(xr1, xi1);
  ex1_store(xr0, xi0, sre, sim, l);  WBAR();
  ex1_load (xr0, xi0, sre, sim, base2); WBAR();
  ex1_store(xr1, xi1, sre, sim, l);  WBAR();
  ex1_load (xr1, xi1, sre, sim, base2); WBAR();
  stage2(xr0, xi0, twg, j2);
  ex2_store(xr0, xi0, sre, sim, ob); WBAR();
  stage2(xr1, xi1, twg, j2);          // VALU overlaps c0's ex2/stage3 DS traffic
  stage3(xr0, xi0, sre, sim, twg, base2, l); WBAR();
  ex2_store(xr1, xi1, sre, sim, ob); WBAR();
  stage3(xr1, xi1, sre, sim, twg, base2, l);
  WBAR();

  // log-magnitude spectra -> sre (c0) / sim (c1); wave min/max per column
  float lmin0 = 3.4e38f, lmax0 = 0.0f, lmin1 = 3.4e38f, lmax1 = 0.0f;
#pragma unroll
  for (int s = 0; s < 16; ++s) {
    float sp0 = __logf(1.0f + sqrtf(xr0[s]*xr0[s] + xi0[s]*xi0[s]));
    float sp1 = __logf(1.0f + sqrtf(xr1[s]*xr1[s] + xi1[s]*xi1[s]));
    sre[l + 64*s] = sp0;
    sim[l + 64*s] = sp1;
    lmin0 = fminf(lmin0, sp0); lmax0 = fmaxf(lmax0, sp0);
    lmin1 = fminf(lmin1, sp1); lmax1 = fmaxf(lmax1, sp1);
  }
#pragma unroll
  for (int off = 32; off; off >>= 1) {
    lmin0 = fminf(lmin0, __shfl_xor(lmin0, off));
    lmax0 = fmaxf(lmax0, __shfl_xor(lmax0, off));
    lmin1 = fminf(lmin1, __shfl_xor(lmin1, off));
    lmax1 = fmaxf(lmax1, __shfl_xor(lmax1, off));
  }
  if (l == 0) {
    int b0 = bc0 / CH, b1 = bc1 / CH;
    atomicMin(&mnmx[b0],         __float_as_int(lmin0));
    atomicMax(&mnmx[BATCH + b0], __float_as_int(lmax0));
    atomicMin(&mnmx[b1],         __float_as_int(lmin1));
    atomicMax(&mnmx[BATCH + b1], __float_as_int(lmax1));
  }
  WBAR();
  float* T10 = WSf + ((size_t)bc0 << 21) + T1OFF;
  float* T11 = WSf + ((size_t)bc1 << 21) + T1OFF;
  fused_resize_col(sre, T10, sx0, (sx0 != 0) && (sx0 != 512), l);
  fused_resize_col(sim, T11, sx1, (sx1 != 0) && (sx1 != 512), l);
}

// Pass 3: contract v + normalization; fixed 10-tap unrolled inner loop.
__global__ __launch_bounds__(256) void k_resize2(const float2* __restrict__ A,
                                                 const int* __restrict__ mnmx,
                                                 float* __restrict__ out) {
  __shared__ float win[11 * OUTHW];
  const int ow = blockIdx.x % OUTHW;
  const int bc = blockIdx.x / OUTHW;
  const int b  = bc / CH;
  const int t  = threadIdx.x;
  const float* T1 = (const float*)(A + ((size_t)bc << 20)) + T1OFF;
  float x = ((float)ow + 0.5f) * KSCALE - 0.5f;
  int jlo_u = (int)ceilf(x - KSCALE);            // unclamped
  int jlo = jlo_u < 0 ? 0 : jlo_u;
  int jhi = (int)floorf(x + KSCALE); if (jhi > N - 1) jhi = N - 1;
  const int nel = (jhi - jlo + 1) * OUTHW;
  const float* src = T1 + (size_t)jlo * OUTHW;
  for (int e = t; e < nel; e += 256) win[e] = src[e];
  __syncthreads();
  const float mn = __int_as_float(mnmx[b]);
  const float mx = __int_as_float(mnmx[BATCH + b]);
  const float inv = 1.0f / (mx - mn + 1e-8f);
  if (t < OUTHW) {
    float ssum = 0.0f, acc = 0.0f;
#pragma unroll
    for (int u = 0; u < 10; ++u) {
      int j = jlo_u + u;
      float wv = 1.0f - fabsf((float)j - x) * SCALE;
      wv = fmaxf(wv, 0.0f);
      bool valid = (j >= 0) && (j <= N - 1);
      if (!valid) wv = 0.0f;
      // wv>0 && valid  =>  jlo <= j <= jhi, so the staged row exists; otherwise
      // read row 0 (always staged) with weight 0 to avoid 0*garbage NaNs.
      int ja = (valid && wv > 0.0f) ? (j - jlo) : 0;
      ssum += wv;
      acc += wv * win[ja * OUTHW + t];
    }
    float v = acc / ssum;
    out[((size_t)bc * OUTHW + t) * OUTHW + ow] = (v - mn) * inv;
  }
}

extern "C" void kernel_launch(void* const* d_in, const int* in_sizes, int n_in,
                              void* d_out, int out_size, void* d_ws, size_t ws_size,
                              hipStream_t stream) {
  const float* in = (const float*)d_in[0];
  float* out = (float*)d_out;
  float2* A = (float2*)d_ws;
  float* WSf = (float*)d_ws;
  int* mnmx = (int*)((char*)d_ws + ABYTES);
  float2* twg = (float2*)((char*)d_ws + ABYTES + 128);

  k_init<<<4, 256, 0, stream>>>(twg, mnmx);
  k_rowfft<<<BC * 128, 256, 0, stream>>>(in, A, twg);
  k_colfft<<<(BC * 513) / 8, 256, 0, stream>>>(A, WSf, mnmx, twg);  // 3078 blocks, 2 cols/wave
  k_resize2<<<BC * OUTHW, 256, 0, stream>>>(A, mnmx, out);
}